// Round 5
// baseline (28.166 us; speedup 1.0000x reference)
//
#include <hip/hip_runtime.h>

// h[d,t] = sum_o R[d,o] * lam[d,o]^t,  lam = exp(-exp(p+gamma))
// D=2048, ORDER=64, L=2048. Output (1, D, L) float32.
//
// Phase A: per-(d,o) constant records -> d_ws (4 MB):
//   rec = { gl2=log2(lam), r, lam, lam^2 | lam^3, lam^256, -, - }
// Phase B: 8192 waves (8/SIMD). Wave = (d, quarter q). Lane l owns
//   t = 512q + 256k + 4l + j, k in {0,1}, j in 0..3.
//   Per mode: a = r*exp2(gl2*(4l+512q)); 4 FMA; a*=lam^256; 4 FMA.
//   No LDS, no shfl, no DS ops; constants via wave-uniform loads.

#define DMODEL 2048
#define ORDER  64
#define SEQLEN 2048

__global__ __launch_bounds__(256) void imf_const_kernel(
    const float* __restrict__ gamma,
    const float* __restrict__ R,
    const float* __restrict__ p,
    float4* __restrict__ cst)
{
    const int i = blockIdx.x * 256 + threadIdx.x;   // i = d*64 + o
    const float LOG2E = 1.44269504088896340736f;
    const float gg = gamma[i];
    const float pp = p[i];
    const float rr = R[i];
    const float gl2  = -__builtin_amdgcn_exp2f((pp + gg) * LOG2E) * LOG2E;
    const float m1   = __builtin_amdgcn_exp2f(gl2);
    const float m2   = m1 * m1;
    const float m3   = m2 * m1;
    const float L256 = __builtin_amdgcn_exp2f(gl2 * 256.0f);
    cst[2 * i]     = make_float4(gl2, rr, m1, m2);
    cst[2 * i + 1] = make_float4(m3, L256, 0.0f, 0.0f);
}

__global__ __launch_bounds__(256) void imf_main_kernel(
    const float4* __restrict__ cst,
    float* __restrict__ out)
{
    const int wave = threadIdx.x >> 6;
    const int lane = threadIdx.x & 63;
    const int wid  = blockIdx.x * 4 + wave;
    const int d    = wid >> 2;
    const int q    = wid & 3;

    const float t4q = (float)(4 * lane + 512 * q);

    // wave-uniform record base -> scalar loads
    const int rec0 = __builtin_amdgcn_readfirstlane(d * ORDER * 2);

    float acc[2][4];
#pragma unroll
    for (int k = 0; k < 2; ++k)
#pragma unroll
        for (int j = 0; j < 4; ++j) acc[k][j] = 0.0f;

#pragma unroll 8
    for (int o = 0; o < ORDER; ++o) {
        const float4 c0 = cst[rec0 + 2 * o];
        const float4 c1 = cst[rec0 + 2 * o + 1];
        float a = __builtin_amdgcn_exp2f(c0.x * t4q) * c0.y;  // r * lam^(4l+512q)
        acc[0][0] += a;
        acc[0][1] += a * c0.z;
        acc[0][2] += a * c0.w;
        acc[0][3] += a * c1.x;
        a *= c1.y;                                            // advance 256
        acc[1][0] += a;
        acc[1][1] += a * c0.z;
        acc[1][2] += a * c0.w;
        acc[1][3] += a * c1.x;
    }

    float* od = out + (size_t)d * SEQLEN + 512 * q + 4 * lane;
    *reinterpret_cast<float4*>(od) =
        make_float4(acc[0][0], acc[0][1], acc[0][2], acc[0][3]);
    *reinterpret_cast<float4*>(od + 256) =
        make_float4(acc[1][0], acc[1][1], acc[1][2], acc[1][3]);
}

// ---- fallback (R4 structure) if ws is too small ----
__global__ __launch_bounds__(256) void imf_fallback_kernel(
    const float* __restrict__ gamma,
    const float* __restrict__ R,
    const float* __restrict__ p,
    float* __restrict__ out)
{
    const int wave = threadIdx.x >> 6;
    const int lane = threadIdx.x & 63;
    const int d    = blockIdx.x * 2 + (wave >> 1);
    const int th   = wave & 1;
    const float tbase = 1024.0f * (float)th;

    __shared__ float cst[4][ORDER][8];
    const float LOG2E = 1.44269504088896340736f;
    {
        const float gg = gamma[d * ORDER + lane];
        const float pp = p[d * ORDER + lane];
        const float rr = R[d * ORDER + lane];
        const float gl2 = -__builtin_amdgcn_exp2f((pp + gg) * LOG2E) * LOG2E;
        const float m1  = __builtin_amdgcn_exp2f(gl2);
        const float m2  = m1 * m1;
        const float m3  = m2 * m1;
        const float L   = __builtin_amdgcn_exp2f(gl2 * 256.0f);
        const float reff = rr * __builtin_amdgcn_exp2f(gl2 * tbase);
        float4* c4 = reinterpret_cast<float4*>(&cst[wave][lane][0]);
        c4[0] = make_float4(gl2, reff, m1, m2);
        c4[1] = make_float4(m3, L, 0.0f, 0.0f);
    }
    __syncthreads();

    float acc[4][4];
#pragma unroll
    for (int k = 0; k < 4; ++k)
#pragma unroll
        for (int j = 0; j < 4; ++j) acc[k][j] = 0.0f;

    const float t4 = 4.0f * (float)lane;
#pragma unroll 4
    for (int o = 0; o < ORDER; ++o) {
        const float4 c0 = *reinterpret_cast<const float4*>(&cst[wave][o][0]);
        const float4 c1 = *reinterpret_cast<const float4*>(&cst[wave][o][4]);
        float a = __builtin_amdgcn_exp2f(c0.x * t4) * c0.y;
#pragma unroll
        for (int k = 0; k < 4; ++k) {
            acc[k][0] += a;
            acc[k][1] += a * c0.z;
            acc[k][2] += a * c0.w;
            acc[k][3] += a * c1.x;
            a *= c1.y;
        }
    }

    float* od = out + (size_t)d * SEQLEN + (int)tbase;
#pragma unroll
    for (int k = 0; k < 4; ++k) {
        *reinterpret_cast<float4*>(od + k * 256 + 4 * lane) =
            make_float4(acc[k][0], acc[k][1], acc[k][2], acc[k][3]);
    }
}

extern "C" void kernel_launch(void* const* d_in, const int* in_sizes, int n_in,
                              void* d_out, int out_size, void* d_ws, size_t ws_size,
                              hipStream_t stream) {
    const float* gamma = (const float*)d_in[0];
    const float* R     = (const float*)d_in[1];
    const float* p     = (const float*)d_in[2];
    float* out = (float*)d_out;

    const size_t need = (size_t)DMODEL * ORDER * 8 * sizeof(float);  // 4 MB
    if (ws_size >= need) {
        float4* cst = (float4*)d_ws;
        imf_const_kernel<<<dim3(DMODEL * ORDER / 256), dim3(256), 0, stream>>>(
            gamma, R, p, cst);
        imf_main_kernel<<<dim3(DMODEL), dim3(256), 0, stream>>>(cst, out);
    } else {
        imf_fallback_kernel<<<dim3(DMODEL / 2), dim3(256), 0, stream>>>(
            gamma, R, p, out);
    }
}

// Round 6
// 11.881 us; speedup vs baseline: 2.3706x; 2.3706x over previous
//
#include <hip/hip_runtime.h>
#include <hip/hip_bf16.h>

// h[d,t] = sum_o R[d,o] * lam[d,o]^t,  lam = exp(-exp(p+gamma))
// D=2048, ORDER=64, L=2048. Output (1, D, L) float32.
//
// MFMA form: t = 32*t1 + t0, t1 in [0,64), t0 in [0,32).
//   H_d[t1,t0] = sum_o A[t1,o] * B[o,t0],
//   A[t1,o] = R[d,o]*exp2(gl2[d,o]*32*t1),  B[o,t0] = exp2(gl2[d,o]*t0)
// One wave per d; C = two 32x32 tiles (t1 0..31 / 32..63), K=64 in 4 steps
// of v_mfma_f32_32x32x16_bf16. bf16 hi/lo split, 3 products (err ~2^-17).
//
// Layouts (gfx950 32x32x16): A: row=lane&31, k=8*(lane>>5)+j
//                            B: col=lane&31, k=8*(lane>>5)+j
//                            C: col=lane&31, row=(r&3)+8*(r>>2)+4*(lane>>5)

#define DMODEL 2048
#define ORDER  64
#define SEQLEN 2048

typedef __attribute__((ext_vector_type(8))) __bf16 bf16x8;
typedef __attribute__((ext_vector_type(16))) float f32x16;

__global__ __launch_bounds__(256) void imf_mfma_kernel(
    const float* __restrict__ gamma,
    const float* __restrict__ R,
    const float* __restrict__ p,
    float* __restrict__ out)
{
    const int tid  = threadIdx.x;
    const int wave = tid >> 6;
    const int lane = tid & 63;
    const int d    = blockIdx.x * 4 + wave;

    __shared__ float2 cst[4][ORDER];   // {gl2 = log2(lambda), R}

    // phase 0: one thread per (d,o) const; fully coalesced loads, 1 exp2
    {
        const int i = blockIdx.x * 256 + tid;        // == d*64 + lane
        const float LOG2E = 1.44269504088896340736f;
        const float gg = gamma[i];
        const float pp = p[i];
        const float rr = R[i];
        const float gl2 = -__builtin_amdgcn_exp2f((pp + gg) * LOG2E) * LOG2E;
        cst[wave][lane] = make_float2(gl2, rr);
    }
    __syncthreads();

    const int   row = lane & 31;     // A row (t1 in tile) == B col (t0)
    const int   hl  = lane >> 5;
    const float frow = (float)row;

    f32x16 acc0, acc1;
#pragma unroll
    for (int r = 0; r < 16; ++r) { acc0[r] = 0.0f; acc1[r] = 0.0f; }

#pragma unroll
    for (int kk = 0; kk < 4; ++kk) {
        const int ob = 16 * kk + 8 * hl;             // this lane's k-chunk base (o)
        bf16x8 ah, al, a2h, a2l, bh, bl;
#pragma unroll
        for (int j = 0; j < 8; ++j) {
            const float2 c = cst[wave][ob + j];      // broadcast LDS read
            const float gl2 = c.x, rr = c.y;
            // A tile0: R * lam^(32*row);  A tile1: rows +32
            const float a  = rr * __builtin_amdgcn_exp2f(gl2 * (32.0f * frow));
            const float a2 = rr * __builtin_amdgcn_exp2f(gl2 * (32.0f * (frow + 32.0f)));
            // B: lam^t0
            const float b  = __builtin_amdgcn_exp2f(gl2 * frow);

            const __bf16 ah_j = (__bf16)a;
            const __bf16 a2h_j = (__bf16)a2;
            const __bf16 bh_j = (__bf16)b;
            ah[j]  = ah_j;   al[j]  = (__bf16)(a  - (float)ah_j);
            a2h[j] = a2h_j;  a2l[j] = (__bf16)(a2 - (float)a2h_j);
            bh[j]  = bh_j;   bl[j]  = (__bf16)(b  - (float)bh_j);
        }
        acc0 = __builtin_amdgcn_mfma_f32_32x32x16_bf16(ah,  bh, acc0, 0, 0, 0);
        acc0 = __builtin_amdgcn_mfma_f32_32x32x16_bf16(al,  bh, acc0, 0, 0, 0);
        acc0 = __builtin_amdgcn_mfma_f32_32x32x16_bf16(ah,  bl, acc0, 0, 0, 0);
        acc1 = __builtin_amdgcn_mfma_f32_32x32x16_bf16(a2h, bh, acc1, 0, 0, 0);
        acc1 = __builtin_amdgcn_mfma_f32_32x32x16_bf16(a2l, bh, acc1, 0, 0, 0);
        acc1 = __builtin_amdgcn_mfma_f32_32x32x16_bf16(a2h, bl, acc1, 0, 0, 0);
    }

    // store: out[d*2048 + 32*t1 + t0], t0 = row, t1 = (r&3)+8*(r>>2)+4*hl (+32 tile1)
    float* od = out + (size_t)d * SEQLEN;
#pragma unroll
    for (int r = 0; r < 16; ++r) {
        const int t1 = (r & 3) + 8 * (r >> 2) + 4 * hl;
        od[32 * t1 + row]        = acc0[r];
        od[32 * (t1 + 32) + row] = acc1[r];
    }
}

extern "C" void kernel_launch(void* const* d_in, const int* in_sizes, int n_in,
                              void* d_out, int out_size, void* d_ws, size_t ws_size,
                              hipStream_t stream) {
    const float* gamma = (const float*)d_in[0];
    const float* R     = (const float*)d_in[1];
    const float* p     = (const float*)d_in[2];
    float* out = (float*)d_out;

    imf_mfma_kernel<<<dim3(DMODEL / 4), dim3(256), 0, stream>>>(gamma, R, p, out);
}